// Round 7
// baseline (138.352 us; speedup 1.0000x reference)
//
#include <hip/hip_runtime.h>

// Neural stack, closed form, single kernel. Round 7: dual-row interleaved
// walks (ILP), peeled chunk-0 with top-row prefetch, f32 DPP prologue scans.
//
// s_j^(t) = relu(d_j - relu(max_{j<tau<=t} G_tau - H_j)),
//   G_tau = U_tau - Dp_{tau-1}, H_j = U_j - Dp_j  (prefix sums of u, d).
// Per row t (p = t - j): M = exclusive prefix-MAX of G (p-order), C =
// exclusive prefix-SUM of s, coeff = min(s, relu(1-C)); exactly 0 once C>=1.
//
// Block (g,b), g in [0,16): rows t = g + 16k, k in [0,32). 8 waves x 4 rows,
// paired (k, k+16) -> (t, t+256): both rows of a pair run in straight-line
// predicated code so their LDS/DPP/gather chains interleave (2x ILP).

#define TT 512
#define BB 128
#define EE 256
#define VS (BB * EE / 4)   // float4 stride between t-rows of v

template <int CTRL, int RM>
__device__ __forceinline__ float dppmov(float o, float s) {
  return __int_as_float(__builtin_amdgcn_update_dpp(
      __float_as_int(o), __float_as_int(s), CTRL, RM, 0xf, false));
}

__device__ __forceinline__ float readlanef(float v, int l) {
  return __int_as_float(__builtin_amdgcn_readlane(__float_as_int(v), l));
}

// wave64 inclusive max-scan (identity -inf)
__device__ __forceinline__ float scan_max64(float v) {
  const float NI = -__builtin_inff();
  v = fmaxf(v, dppmov<0x111, 0xf>(NI, v));   // row_shr:1
  v = fmaxf(v, dppmov<0x112, 0xf>(NI, v));   // row_shr:2
  v = fmaxf(v, dppmov<0x114, 0xf>(NI, v));   // row_shr:4
  v = fmaxf(v, dppmov<0x118, 0xf>(NI, v));   // row_shr:8
  v = fmaxf(v, dppmov<0x142, 0xa>(NI, v));   // row_bcast:15 -> rows 1,3
  v = fmaxf(v, dppmov<0x143, 0xc>(NI, v));   // row_bcast:31 -> rows 2,3
  return v;
}

// wave64 inclusive sum-scan (identity 0)
__device__ __forceinline__ float scan_add64(float v) {
  v += dppmov<0x111, 0xf>(0.f, v);
  v += dppmov<0x112, 0xf>(0.f, v);
  v += dppmov<0x114, 0xf>(0.f, v);
  v += dppmov<0x118, 0xf>(0.f, v);
  v += dppmov<0x142, 0xa>(0.f, v);
  v += dppmov<0x143, 0xc>(0.f, v);
  return v;
}

// whole-wave shift right by 1 (lane0 <- carry)
__device__ __forceinline__ float wshr1(float carry, float v) {
  return __int_as_float(__builtin_amdgcn_update_dpp(
      __float_as_int(carry), __float_as_int(v), 0x138, 0xf, 0xf, false));
}

__launch_bounds__(512)
__global__ void stack_kernel(const float* __restrict__ v,
                             const float* __restrict__ u,
                             const float* __restrict__ d,
                             float* __restrict__ out) {
  const int b = blockIdx.x & (BB - 1);
  const int g = blockIdx.x >> 7;            // stripe id, 0..15
  const int tid = threadIdx.x;
  const int wave = tid >> 6;
  const int lane = tid & 63;
  const float NI = -__builtin_inff();

  __shared__ float sG[TT], sH[TT], sd[TT];
  __shared__ float segU[8], segD[8];

  // ---- prologue: stage u,d + f32 DPP segmented scans -> G,H (one pass) ----
  {
    const int i = tid;                      // 512 threads == TT entries
    float uv = u[i * BB + b];
    float dv = d[i * BB + b];
    sd[i] = dv;
    float su = scan_add64(uv);              // inclusive within 64-entry seg
    float sv = scan_add64(dv);
    if (lane == 63) { segU[wave] = su; segD[wave] = sv; }
    __syncthreads();
    float oU = 0.f, oD = 0.f;
    for (int w2 = 0; w2 < wave; ++w2) { oU += segU[w2]; oD += segD[w2]; }
    float U = su + oU;
    float D = sv + oD;
    sG[i] = U - (D - dv);                   // G_t = U_t - Dp_{t-1}
    sH[i] = U - D;                          // H_t = U_t - Dp_t
    __syncthreads();
  }

  const float4* vb = (const float4*)(v + b * EE);

  for (int q = 0; q < 2; ++q) {
    const int ta = g + 16 * (wave + 8 * q);   // [0, 255]
    const int tb = ta + 256;                  // [256, 511]

    // prefetch top rows (j = t always contributes unless d_t == 0)
    float4 ya = vb[(size_t)ta * VS + lane];
    float4 yb = vb[(size_t)tb * VS + lane];
    float4 acc_a; acc_a.x = 0.f; acc_a.y = 0.f; acc_a.z = 0.f; acc_a.w = 0.f;
    float4 acc_b = acc_a;

    // ---- peeled chunk 0, both rows straight-line ----
    const int ja = ta - lane;
    const bool ina = (lane <= ta);
    const int jb = tb - lane;                 // lane <= 63 < 256 <= tb: always in
    float Ga = ina ? sG[ina ? ja : 0] : NI;
    float Ha = ina ? sH[ina ? ja : 0] : 0.f;
    float da = ina ? sd[ina ? ja : 0] : 0.f;
    float Gb = sG[jb];
    float Hb = sH[jb];
    float db = sd[jb];

    float gma = scan_max64(Ga);
    float gmb = scan_max64(Gb);
    float Mea = wshr1(NI, gma);
    float Meb = wshr1(NI, gmb);
    float sa = fmaxf(da - fmaxf(Mea - Ha, 0.f), 0.f);
    float sb = fmaxf(db - fmaxf(Meb - Hb, 0.f), 0.f);
    float csa = scan_add64(sa);
    float csb = scan_add64(sb);
    float Cea = wshr1(0.f, csa);
    float Ceb = wshr1(0.f, csb);
    float ca = fminf(sa, fmaxf(1.f - Cea, 0.f));
    float cb = fminf(sb, fmaxf(1.f - Ceb, 0.f));

    // top entries via prefetched rows
    float c0a = readlanef(ca, 0);
    float c0b = readlanef(cb, 0);
    acc_a.x += c0a * ya.x; acc_a.y += c0a * ya.y;
    acc_a.z += c0a * ya.z; acc_a.w += c0a * ya.w;
    acc_b.x += c0b * yb.x; acc_b.y += c0b * yb.y;
    acc_b.z += c0b * yb.z; acc_b.w += c0b * yb.w;

    unsigned long long ma = __ballot(ca > 0.f) & ~1ull;
    unsigned long long mb = __ballot(cb > 0.f) & ~1ull;
    // fused gather: a/b loads alternate -> 2 outstanding
    while (ma | mb) {
      if (ma) {
        int l = __ffsll(ma) - 1; ma &= ma - 1;
        float c = readlanef(ca, l);
        float4 y = vb[(size_t)(ta - l) * VS + lane];
        acc_a.x += c * y.x; acc_a.y += c * y.y;
        acc_a.z += c * y.z; acc_a.w += c * y.w;
      }
      if (mb) {
        int l = __ffsll(mb) - 1; mb &= mb - 1;
        float c = readlanef(cb, l);
        float4 y = vb[(size_t)(tb - l) * VS + lane];
        acc_b.x += c * y.x; acc_b.y += c * y.y;
        acc_b.z += c * y.z; acc_b.w += c * y.w;
      }
    }

    float Ca = readlanef(csa, 63);
    float Cb = readlanef(csb, 63);
    float Ma = readlanef(gma, 63);
    float Mb = readlanef(gmb, 63);
    bool aa = (Ca < 1.f) && (ta >= 64);
    bool ab = (Cb < 1.f);                     // tb >= 256: chunk 1 always exists

    // ---- tail chunks (rare: stack mass < 1), both rows predicated ----
    for (int base = 64; aa | ab; base += 64) {
      const int p = base + lane;
      const bool ina2 = aa && (p <= ta);
      const bool inb2 = ab && (p <= tb);
      const int ja2 = ina2 ? (ta - p) : 0;
      const int jb2 = inb2 ? (tb - p) : 0;
      float Ga2 = ina2 ? sG[ja2] : NI;
      float Ha2 = ina2 ? sH[ja2] : 0.f;
      float da2 = ina2 ? sd[ja2] : 0.f;
      float Gb2 = inb2 ? sG[jb2] : NI;
      float Hb2 = inb2 ? sH[jb2] : 0.f;
      float db2 = inb2 ? sd[jb2] : 0.f;

      float gma2 = scan_max64(Ga2);
      float gmb2 = scan_max64(Gb2);
      float Mea2 = fmaxf(wshr1(Ma, gma2), Ma);
      float Meb2 = fmaxf(wshr1(Mb, gmb2), Mb);
      float sa2 = fmaxf(da2 - fmaxf(Mea2 - Ha2, 0.f), 0.f);
      float sb2 = fmaxf(db2 - fmaxf(Meb2 - Hb2, 0.f), 0.f);
      float csa2 = scan_add64(sa2);
      float csb2 = scan_add64(sb2);
      float Cea2 = wshr1(0.f, csa2) + Ca;
      float Ceb2 = wshr1(0.f, csb2) + Cb;
      float ca2 = fminf(sa2, fmaxf(1.f - Cea2, 0.f));
      float cb2 = fminf(sb2, fmaxf(1.f - Ceb2, 0.f));

      unsigned long long ma2 = __ballot(ca2 > 0.f);
      unsigned long long mb2 = __ballot(cb2 > 0.f);
      while (ma2 | mb2) {
        if (ma2) {
          int l = __ffsll(ma2) - 1; ma2 &= ma2 - 1;
          float c = readlanef(ca2, l);
          float4 y = vb[(size_t)(ta - base - l) * VS + lane];
          acc_a.x += c * y.x; acc_a.y += c * y.y;
          acc_a.z += c * y.z; acc_a.w += c * y.w;
        }
        if (mb2) {
          int l = __ffsll(mb2) - 1; mb2 &= mb2 - 1;
          float c = readlanef(cb2, l);
          float4 y = vb[(size_t)(tb - base - l) * VS + lane];
          acc_b.x += c * y.x; acc_b.y += c * y.y;
          acc_b.z += c * y.z; acc_b.w += c * y.w;
        }
      }

      Ca += readlanef(csa2, 63);
      Cb += readlanef(csb2, 63);
      Ma = fmaxf(Ma, readlanef(gma2, 63));
      Mb = fmaxf(Mb, readlanef(gmb2, 63));
      aa = aa && (Ca < 1.f) && (base + 64 <= ta);
      ab = ab && (Cb < 1.f) && (base + 64 <= tb);
    }

    ((float4*)(out + ((size_t)ta * BB + b) * EE))[lane] = acc_a;
    ((float4*)(out + ((size_t)tb * BB + b) * EE))[lane] = acc_b;
  }
}

extern "C" void kernel_launch(void* const* d_in, const int* in_sizes, int n_in,
                              void* d_out, int out_size, void* d_ws, size_t ws_size,
                              hipStream_t stream) {
  const float* v = (const float*)d_in[0];
  const float* u = (const float*)d_in[1];
  const float* dd = (const float*)d_in[2];
  float* out = (float*)d_out;
  (void)in_sizes; (void)n_in; (void)out_size; (void)d_ws; (void)ws_size;

  hipLaunchKernelGGL(stack_kernel, dim3(16 * BB), dim3(512), 0, stream,
                     v, u, dd, out);
}

// Round 8
// 134.357 us; speedup vs baseline: 1.0297x; 1.0297x over previous
//
#include <hip/hip_runtime.h>

// Neural stack, closed form, single kernel. Round 8: phase-separated batches —
// per wave, 4 rows' scans run back-to-back (8 interleaved DPP chains), then
// one fused gather loop keeps 4 independent L2 loads in flight; top-row
// v-lines prefetched before the scans. Round-6 row striping / 256-thr blocks
// (lowest-FETCH config). Rare deep rows (C<1 past 64 entries) take a
// predicated per-row tail loop.
//
// s_j^(t) = relu(d_j - relu(max_{j<tau<=t} G_tau - H_j)),
//   G_tau = U_tau - Dp_{tau-1}, H_j = U_j - Dp_j  (prefix sums of u, d).
// Per row t (p = t - j): M = exclusive prefix-MAX of G (p-order), C =
// exclusive prefix-SUM of s, coeff = min(s, relu(1-C)); exactly 0 once C>=1.

#define TT 512
#define BB 128
#define EE 256
#define VS (BB * EE / 4)   // float4 stride between t-rows of v

template <int CTRL, int RM>
__device__ __forceinline__ float dppmov(float o, float s) {
  return __int_as_float(__builtin_amdgcn_update_dpp(
      __float_as_int(o), __float_as_int(s), CTRL, RM, 0xf, false));
}

__device__ __forceinline__ float readlanef(float v, int l) {
  return __int_as_float(__builtin_amdgcn_readlane(__float_as_int(v), l));
}

// wave64 inclusive max-scan (identity -inf)
__device__ __forceinline__ float scan_max64(float v) {
  const float NI = -__builtin_inff();
  v = fmaxf(v, dppmov<0x111, 0xf>(NI, v));   // row_shr:1
  v = fmaxf(v, dppmov<0x112, 0xf>(NI, v));   // row_shr:2
  v = fmaxf(v, dppmov<0x114, 0xf>(NI, v));   // row_shr:4
  v = fmaxf(v, dppmov<0x118, 0xf>(NI, v));   // row_shr:8
  v = fmaxf(v, dppmov<0x142, 0xa>(NI, v));   // row_bcast:15 -> rows 1,3
  v = fmaxf(v, dppmov<0x143, 0xc>(NI, v));   // row_bcast:31 -> rows 2,3
  return v;
}

// wave64 inclusive sum-scan (identity 0)
__device__ __forceinline__ float scan_add64(float v) {
  v += dppmov<0x111, 0xf>(0.f, v);
  v += dppmov<0x112, 0xf>(0.f, v);
  v += dppmov<0x114, 0xf>(0.f, v);
  v += dppmov<0x118, 0xf>(0.f, v);
  v += dppmov<0x142, 0xa>(0.f, v);
  v += dppmov<0x143, 0xc>(0.f, v);
  return v;
}

// whole-wave shift right by 1 (lane0 <- carry)
__device__ __forceinline__ float wshr1(float carry, float v) {
  return __int_as_float(__builtin_amdgcn_update_dpp(
      __float_as_int(carry), __float_as_int(v), 0x138, 0xf, 0xf, false));
}

__launch_bounds__(256)
__global__ void stack_kernel(const float* __restrict__ v,
                             const float* __restrict__ u,
                             const float* __restrict__ d,
                             float* __restrict__ out) {
  const int b = blockIdx.x & (BB - 1);
  const int g = blockIdx.x >> 7;            // stripe id, 0..15
  const int tid = threadIdx.x;
  const int wave = tid >> 6;
  const int lane = tid & 63;
  const float NI = -__builtin_inff();

  __shared__ float sG[TT], sH[TT], sd[TT];
  __shared__ float segU[4], segD[4];

  // ---- prologue: f32 DPP segmented scans -> G,H (128 entries per wave) ----
  {
    float cU = 0.f, cD = 0.f;
    const int i0 = wave * 128;
#pragma unroll
    for (int c = 0; c < 2; ++c) {
      const int i = i0 + c * 64 + lane;
      float uv = u[i * BB + b];
      float dv = d[i * BB + b];
      sd[i] = dv;
      float su = scan_add64(uv);
      float sv = scan_add64(dv);
      float U = cU + su;
      float D = cD + sv;
      sG[i] = U - (D - dv);                 // G_t = U_t - Dp_{t-1} (local)
      sH[i] = U - D;                        // H_t = U_t - Dp_t (local)
      cU += readlanef(su, 63);
      cD += readlanef(sv, 63);
    }
    if (lane == 0) { segU[wave] = cU; segD[wave] = cD; }
  }
  __syncthreads();
  // fixup: add (oU - oD) of preceding 128-segments to both G and H
  for (int i = tid; i < TT; i += 256) {
    const int ws = i >> 7;
    float o = 0.f;
    for (int w2 = 0; w2 < ws; ++w2) o += segU[w2] - segD[w2];
    sG[i] += o;
    sH[i] += o;
  }
  __syncthreads();

  const float4* vb = (const float4*)(v + b * EE);

  for (int q = 0; q < 2; ++q) {
    int t[4];
#pragma unroll
    for (int r = 0; r < 4; ++r) t[r] = g + 16 * (wave + 4 * (r + 4 * q));

    // ---- prefetch top v-lines (hide under scan phase) ----
    float4 ytop[4];
#pragma unroll
    for (int r = 0; r < 4; ++r) ytop[r] = vb[(size_t)t[r] * VS + lane];

    // ---- phase 1: 4 rows' scans back-to-back (independent DPP chains) ----
    float coef[4], Ccar[4], Mcar[4];
    unsigned long long mask[4];
#pragma unroll
    for (int r = 0; r < 4; ++r) {
      const int tr = t[r];
      const bool in = (lane <= tr);
      const int j = in ? tr - lane : 0;
      float Gv = in ? sG[j] : NI;
      float Hv = in ? sH[j] : 0.f;
      float dv = in ? sd[j] : 0.f;
      float gmax = scan_max64(Gv);
      float Mex = wshr1(NI, gmax);
      float s = fmaxf(dv - fmaxf(Mex - Hv, 0.f), 0.f);
      float csum = scan_add64(s);
      float Cex = wshr1(0.f, csum);
      float cf = fminf(s, fmaxf(1.f - Cex, 0.f));
      coef[r] = cf;
      mask[r] = __ballot(cf > 0.f) & ~1ull;   // bit 0 handled via ytop
      Ccar[r] = readlanef(csum, 63);
      Mcar[r] = readlanef(gmax, 63);
    }

    // ---- top contributions ----
    float4 acc[4];
#pragma unroll
    for (int r = 0; r < 4; ++r) {
      float c0 = readlanef(coef[r], 0);
      acc[r].x = c0 * ytop[r].x; acc[r].y = c0 * ytop[r].y;
      acc[r].z = c0 * ytop[r].z; acc[r].w = c0 * ytop[r].w;
    }

    // ---- phase 2: fused gather, 4 independent loads in flight ----
    while (mask[0] | mask[1] | mask[2] | mask[3]) {
#pragma unroll
      for (int r = 0; r < 4; ++r) {
        if (mask[r]) {                        // wave-uniform
          int l = __ffsll(mask[r]) - 1;
          mask[r] &= mask[r] - 1;
          float c = readlanef(coef[r], l);
          float4 y = vb[(size_t)(t[r] - l) * VS + lane];
          acc[r].x += c * y.x; acc[r].y += c * y.y;
          acc[r].z += c * y.z; acc[r].w += c * y.w;
        }
      }
    }

    // ---- phase 3: rare deep-row tails (stack mass < 1 past 64 entries) ----
#pragma unroll
    for (int r = 0; r < 4; ++r) {
      if (Ccar[r] < 1.f && t[r] >= 64) {      // wave-uniform
        float Ca = Ccar[r], Ma = Mcar[r];
        const int tr = t[r];
        for (int base = 64;; base += 64) {
          const int p = base + lane;
          const bool in = (p <= tr);
          const int j = in ? tr - p : 0;
          float Gv = in ? sG[j] : NI;
          float Hv = in ? sH[j] : 0.f;
          float dv = in ? sd[j] : 0.f;
          float gmax = scan_max64(Gv);
          float Mex = fmaxf(wshr1(Ma, gmax), Ma);
          float s = fmaxf(dv - fmaxf(Mex - Hv, 0.f), 0.f);
          float csum = scan_add64(s);
          float Cex = wshr1(0.f, csum) + Ca;
          float cf = fminf(s, fmaxf(1.f - Cex, 0.f));
          unsigned long long m = __ballot(cf > 0.f);
          while (m) {
            int l = __ffsll(m) - 1;
            m &= m - 1;
            float c = readlanef(cf, l);
            float4 y = vb[(size_t)(tr - base - l) * VS + lane];
            acc[r].x += c * y.x; acc[r].y += c * y.y;
            acc[r].z += c * y.z; acc[r].w += c * y.w;
          }
          Ca += readlanef(csum, 63);
          Ma = fmaxf(Ma, readlanef(gmax, 63));
          if (Ca >= 1.f || base + 64 > tr) break;
        }
      }
    }

    // ---- stores ----
#pragma unroll
    for (int r = 0; r < 4; ++r) {
      ((float4*)(out + ((size_t)t[r] * BB + b) * EE))[lane] = acc[r];
    }
  }
}

extern "C" void kernel_launch(void* const* d_in, const int* in_sizes, int n_in,
                              void* d_out, int out_size, void* d_ws, size_t ws_size,
                              hipStream_t stream) {
  const float* v = (const float*)d_in[0];
  const float* u = (const float*)d_in[1];
  const float* dd = (const float*)d_in[2];
  float* out = (float*)d_out;
  (void)in_sizes; (void)n_in; (void)out_size; (void)d_ws; (void)ws_size;

  hipLaunchKernelGGL(stack_kernel, dim3(16 * BB), dim3(256), 0, stream,
                     v, u, dd, out);
}